// Round 1
// baseline (195.989 us; speedup 1.0000x reference)
//
#include <hip/hip_runtime.h>

#define BF_STAGES 10
#define BF_DIM 1024

// Pre-kernel: cs[s*512+k] = (cos(angles[s][k]), sin(angles[s][k])), 40 KB in d_ws.
__global__ void bf_fill_cs(const float* __restrict__ angles, float2* __restrict__ cs, int n) {
    int i = blockIdx.x * blockDim.x + threadIdx.x;
    if (i < n) {
        float a = angles[i];
        float s, c;
        sincosf(a, &s, &c);
        cs[i] = make_float2(c, s);
    }
}

// In-place rotate of a register pair.
#define ROT(vi, vj, c, s) do { float _t = (c)*(vi) - (s)*(vj); (vj) = (s)*(vi) + (c)*(vj); (vi) = _t; } while (0)

// One wave == one row of 1024 floats, held entirely in registers.
// Element mapping: e = m_hi*256 + lane*4 + m_lo   (m_hi, m_lo in 0..3, lane in 0..63)
//   stage 0,1  -> bits 0,1 of e  -> intra-float4
//   stage 2..7 -> lane bits 0..5 -> __shfl_xor mask 1<<(s-2)
//   stage 8,9  -> bits 8,9 of e  -> across the four float4s
// Angle index for stage s: k = e with bit s deleted.
// csf4 view: csf4[s*256 + k/2] = (cos[k], sin[k], cos[k+1], sin[k+1]).
__global__ __launch_bounds__(256) void bf_butterfly(const float* __restrict__ x,
                                                    const float4* __restrict__ csf4,
                                                    float* __restrict__ out,
                                                    int n_rows) {
    const int lane = threadIdx.x & 63;
    const int wv   = threadIdx.x >> 6;
    const long long row = (long long)blockIdx.x * 4 + wv;
    if (row >= n_rows) return;

    const float* xr  = x   + row * BF_DIM;
    float*       orr = out + row * BF_DIM;

    float4 v[4];
#pragma unroll
    for (int mh = 0; mh < 4; ++mh)
        v[mh] = *reinterpret_cast<const float4*>(xr + mh * 256 + lane * 4);

    // ---- stage 0: pairs (x,y) and (z,w); k = mh*128 + lane*2 + {0,1}
#pragma unroll
    for (int mh = 0; mh < 4; ++mh) {
        float4 c = csf4[0 * 256 + mh * 64 + lane];
        ROT(v[mh].x, v[mh].y, c.x, c.y);
        ROT(v[mh].z, v[mh].w, c.z, c.w);
    }
    // ---- stage 1: pairs (x,z) and (y,w); same k addresses, stage-1 table
#pragma unroll
    for (int mh = 0; mh < 4; ++mh) {
        float4 c = csf4[1 * 256 + mh * 64 + lane];
        ROT(v[mh].x, v[mh].z, c.x, c.y);
        ROT(v[mh].y, v[mh].w, c.z, c.w);
    }

    // ---- stages 2..7: cross-lane, partner = lane ^ (1<<(s-2))
#pragma unroll
    for (int s = 2; s < 8; ++s) {
        const int b   = s - 2;
        const int msk = 1 << b;
        const int lc  = ((lane >> (b + 1)) << b) | (lane & (msk - 1)); // lane with bit b deleted
        const float sg = (lane & msk) ? 1.0f : -1.0f;                  // j-side: +s, i-side: -s
#pragma unroll
        for (int mh = 0; mh < 4; ++mh) {
            float4 cA = csf4[s * 256 + mh * 64 + lc * 2];     // m_lo 0,1
            float4 cB = csf4[s * 256 + mh * 64 + lc * 2 + 1]; // m_lo 2,3
            float4 w;
            w.x = __shfl_xor(v[mh].x, msk);
            w.y = __shfl_xor(v[mh].y, msk);
            w.z = __shfl_xor(v[mh].z, msk);
            w.w = __shfl_xor(v[mh].w, msk);
            // v' = c*v + sg*s*w   (i-side: c*vi - s*vj ; j-side: s*vi + c*vj)
            v[mh].x = fmaf(sg * cA.y, w.x, cA.x * v[mh].x);
            v[mh].y = fmaf(sg * cA.w, w.y, cA.z * v[mh].y);
            v[mh].z = fmaf(sg * cB.y, w.z, cB.x * v[mh].z);
            v[mh].w = fmaf(sg * cB.w, w.w, cB.z * v[mh].w);
        }
    }

    // ---- stage 8: pairs (v[0],v[1]) k=lane*4+mlo ; (v[2],v[3]) k=256+lane*4+mlo
    {
        float4 a0 = csf4[8 * 256 + lane * 2];
        float4 a1 = csf4[8 * 256 + lane * 2 + 1];
        float4 b0 = csf4[8 * 256 + 128 + lane * 2];
        float4 b1 = csf4[8 * 256 + 128 + lane * 2 + 1];
        ROT(v[0].x, v[1].x, a0.x, a0.y);
        ROT(v[0].y, v[1].y, a0.z, a0.w);
        ROT(v[0].z, v[1].z, a1.x, a1.y);
        ROT(v[0].w, v[1].w, a1.z, a1.w);
        ROT(v[2].x, v[3].x, b0.x, b0.y);
        ROT(v[2].y, v[3].y, b0.z, b0.w);
        ROT(v[2].z, v[3].z, b1.x, b1.y);
        ROT(v[2].w, v[3].w, b1.z, b1.w);
    }
    // ---- stage 9: pairs (v[0],v[2]) k=lane*4+mlo ; (v[1],v[3]) k=256+lane*4+mlo
    {
        float4 a0 = csf4[9 * 256 + lane * 2];
        float4 a1 = csf4[9 * 256 + lane * 2 + 1];
        float4 b0 = csf4[9 * 256 + 128 + lane * 2];
        float4 b1 = csf4[9 * 256 + 128 + lane * 2 + 1];
        ROT(v[0].x, v[2].x, a0.x, a0.y);
        ROT(v[0].y, v[2].y, a0.z, a0.w);
        ROT(v[0].z, v[2].z, a1.x, a1.y);
        ROT(v[0].w, v[2].w, a1.z, a1.w);
        ROT(v[1].x, v[3].x, b0.x, b0.y);
        ROT(v[1].y, v[3].y, b0.z, b0.w);
        ROT(v[1].z, v[3].z, b1.x, b1.y);
        ROT(v[1].w, v[3].w, b1.z, b1.w);
    }

#pragma unroll
    for (int mh = 0; mh < 4; ++mh)
        *reinterpret_cast<float4*>(orr + mh * 256 + lane * 4) = v[mh];
}

extern "C" void kernel_launch(void* const* d_in, const int* in_sizes, int n_in,
                              void* d_out, int out_size, void* d_ws, size_t ws_size,
                              hipStream_t stream) {
    const float* x      = (const float*)d_in[0];
    const float* angles = (const float*)d_in[1];
    float*       out    = (float*)d_out;
    float2*      cs     = (float2*)d_ws;   // 10*512*8 = 40960 bytes

    const int ncs = BF_STAGES * (BF_DIM / 2);
    bf_fill_cs<<<(ncs + 255) / 256, 256, 0, stream>>>(angles, cs, ncs);

    const int rows   = in_sizes[0] / BF_DIM;
    const int blocks = (rows + 3) / 4;   // 4 rows (waves) per 256-thread block
    bf_butterfly<<<blocks, 256, 0, stream>>>(x, (const float4*)cs, out, rows);
}

// Round 2
// 194.470 us; speedup vs baseline: 1.0078x; 1.0078x over previous
//
#include <hip/hip_runtime.h>

#define BF_STAGES 10
#define BF_DIM 1024
#define BF_R 8   // rows per wave: amortizes table loads 8x, gives 8-way ILP on shuffle chains

// Pre-kernel: cs[s*512+k] = (cos(angles[s][k]), sin(angles[s][k])), 40 KB in d_ws.
__global__ void bf_fill_cs(const float* __restrict__ angles, float2* __restrict__ cs, int n) {
    int i = blockIdx.x * blockDim.x + threadIdx.x;
    if (i < n) {
        float a = angles[i];
        float s, c;
        sincosf(a, &s, &c);
        cs[i] = make_float2(c, s);
    }
}

// In-place rotate of a register pair.
#define ROT(vi, vj, c, s) do { float _t = (c)*(vi) - (s)*(vj); (vj) = (s)*(vi) + (c)*(vj); (vi) = _t; } while (0)

// Lane-exchange partner value for xor-mask MSK.
// MSK 1,2 -> DPP quad_perm (VALU pipe, no LDS). MSK 4..32 -> ds_swizzle/bpermute.
template <int MSK>
__device__ __forceinline__ float bf_partner(float x) {
    if constexpr (MSK == 1) {
        // quad_perm [1,0,3,2] = 1 | (0<<2) | (3<<4) | (2<<6) = 0xB1
        return __int_as_float(__builtin_amdgcn_update_dpp(0, __float_as_int(x), 0xB1, 0xF, 0xF, true));
    } else if constexpr (MSK == 2) {
        // quad_perm [2,3,0,1] = 2 | (3<<2) | (0<<4) | (1<<6) = 0x4E
        return __int_as_float(__builtin_amdgcn_update_dpp(0, __float_as_int(x), 0x4E, 0xF, 0xF, true));
    } else {
        return __shfl_xor(x, MSK);
    }
}

// Cross-lane stage S (2..7): lane-bit b = S-2, partner lane = lane ^ (1<<b).
// Angle index k = element index with bit S deleted; per-mh tables cA (m_lo 0,1), cB (m_lo 2,3).
template <int S>
__device__ __forceinline__ void bf_cross_stage(float4 (&v)[BF_R][4], const float4* __restrict__ csf4,
                                               int lane) {
    constexpr int b   = S - 2;
    constexpr int msk = 1 << b;
    const int lc = ((lane >> (b + 1)) << b) | (lane & (msk - 1)); // lane with bit b deleted
    const float sg = (lane & msk) ? 1.0f : -1.0f;                 // j-side: +s, i-side: -s
    float4 cA[4], cB[4];
#pragma unroll
    for (int mh = 0; mh < 4; ++mh) {
        cA[mh] = csf4[S * 256 + mh * 64 + lc * 2];
        cB[mh] = csf4[S * 256 + mh * 64 + lc * 2 + 1];
    }
    // Fold the sign into the sin coefficients once (row-invariant).
    float sAx[4], sAy[4], sBx[4], sBy[4];
#pragma unroll
    for (int mh = 0; mh < 4; ++mh) {
        sAx[mh] = sg * cA[mh].y; sAy[mh] = sg * cA[mh].w;
        sBx[mh] = sg * cB[mh].y; sBy[mh] = sg * cB[mh].w;
    }
#pragma unroll
    for (int r = 0; r < BF_R; ++r) {
#pragma unroll
        for (int mh = 0; mh < 4; ++mh) {
            float4 w;
            w.x = bf_partner<msk>(v[r][mh].x);
            w.y = bf_partner<msk>(v[r][mh].y);
            w.z = bf_partner<msk>(v[r][mh].z);
            w.w = bf_partner<msk>(v[r][mh].w);
            // v' = c*v + sg*s*w   (i-side: c*vi - s*vj ; j-side: s*vi + c*vj)
            v[r][mh].x = fmaf(sAx[mh], w.x, cA[mh].x * v[r][mh].x);
            v[r][mh].y = fmaf(sAy[mh], w.y, cA[mh].z * v[r][mh].y);
            v[r][mh].z = fmaf(sBx[mh], w.z, cB[mh].x * v[r][mh].z);
            v[r][mh].w = fmaf(sBy[mh], w.w, cB[mh].z * v[r][mh].w);
        }
    }
}

// One wave == BF_R consecutive rows of 1024 floats, held entirely in registers.
// Element mapping: e = m_hi*256 + lane*4 + m_lo   (m_hi, m_lo in 0..3, lane in 0..63)
//   stage 0,1  -> bits 0,1 of e  -> intra-float4
//   stage 2..7 -> lane bits 0..5 -> lane exchange, mask 1<<(s-2)
//   stage 8,9  -> bits 8,9 of e  -> across the four float4s
// Angle index for stage s: k = e with bit s deleted.
// csf4 view: csf4[s*256 + k/2] = (cos[k], sin[k], cos[k+1], sin[k+1]).
__global__ __launch_bounds__(256, 2) void bf_butterfly(const float* __restrict__ x,
                                                       const float4* __restrict__ csf4,
                                                       float* __restrict__ out,
                                                       int n_rows) {
    const int lane = threadIdx.x & 63;
    const int wv   = threadIdx.x >> 6;
    const long long row0 = ((long long)blockIdx.x * 4 + wv) * BF_R;
    if (row0 >= n_rows) return;

    const float* xr  = x   + row0 * BF_DIM;
    float*       orr = out + row0 * BF_DIM;

    float4 v[BF_R][4];
#pragma unroll
    for (int r = 0; r < BF_R; ++r) {
        if (row0 + r < n_rows) {
#pragma unroll
            for (int mh = 0; mh < 4; ++mh)
                v[r][mh] = *reinterpret_cast<const float4*>(xr + r * BF_DIM + mh * 256 + lane * 4);
        } else {
#pragma unroll
            for (int mh = 0; mh < 4; ++mh)
                v[r][mh] = make_float4(0.f, 0.f, 0.f, 0.f);
        }
    }

    // ---- stage 0: pairs (x,y) and (z,w); k = mh*128 + lane*2 + {0,1}
    {
        float4 c[4];
#pragma unroll
        for (int mh = 0; mh < 4; ++mh) c[mh] = csf4[0 * 256 + mh * 64 + lane];
#pragma unroll
        for (int r = 0; r < BF_R; ++r)
#pragma unroll
            for (int mh = 0; mh < 4; ++mh) {
                ROT(v[r][mh].x, v[r][mh].y, c[mh].x, c[mh].y);
                ROT(v[r][mh].z, v[r][mh].w, c[mh].z, c[mh].w);
            }
    }
    // ---- stage 1: pairs (x,z) and (y,w); same k addresses, stage-1 table
    {
        float4 c[4];
#pragma unroll
        for (int mh = 0; mh < 4; ++mh) c[mh] = csf4[1 * 256 + mh * 64 + lane];
#pragma unroll
        for (int r = 0; r < BF_R; ++r)
#pragma unroll
            for (int mh = 0; mh < 4; ++mh) {
                ROT(v[r][mh].x, v[r][mh].z, c[mh].x, c[mh].y);
                ROT(v[r][mh].y, v[r][mh].w, c[mh].z, c[mh].w);
            }
    }

    // ---- stages 2..7: cross-lane
    bf_cross_stage<2>(v, csf4, lane);
    bf_cross_stage<3>(v, csf4, lane);
    bf_cross_stage<4>(v, csf4, lane);
    bf_cross_stage<5>(v, csf4, lane);
    bf_cross_stage<6>(v, csf4, lane);
    bf_cross_stage<7>(v, csf4, lane);

    // ---- stage 8: pairs (v[0],v[1]) k=lane*4+mlo ; (v[2],v[3]) k=256+lane*4+mlo
    {
        float4 a0 = csf4[8 * 256 + lane * 2];
        float4 a1 = csf4[8 * 256 + lane * 2 + 1];
        float4 b0 = csf4[8 * 256 + 128 + lane * 2];
        float4 b1 = csf4[8 * 256 + 128 + lane * 2 + 1];
#pragma unroll
        for (int r = 0; r < BF_R; ++r) {
            ROT(v[r][0].x, v[r][1].x, a0.x, a0.y);
            ROT(v[r][0].y, v[r][1].y, a0.z, a0.w);
            ROT(v[r][0].z, v[r][1].z, a1.x, a1.y);
            ROT(v[r][0].w, v[r][1].w, a1.z, a1.w);
            ROT(v[r][2].x, v[r][3].x, b0.x, b0.y);
            ROT(v[r][2].y, v[r][3].y, b0.z, b0.w);
            ROT(v[r][2].z, v[r][3].z, b1.x, b1.y);
            ROT(v[r][2].w, v[r][3].w, b1.z, b1.w);
        }
    }
    // ---- stage 9: pairs (v[0],v[2]) k=lane*4+mlo ; (v[1],v[3]) k=256+lane*4+mlo
    {
        float4 a0 = csf4[9 * 256 + lane * 2];
        float4 a1 = csf4[9 * 256 + lane * 2 + 1];
        float4 b0 = csf4[9 * 256 + 128 + lane * 2];
        float4 b1 = csf4[9 * 256 + 128 + lane * 2 + 1];
#pragma unroll
        for (int r = 0; r < BF_R; ++r) {
            ROT(v[r][0].x, v[r][2].x, a0.x, a0.y);
            ROT(v[r][0].y, v[r][2].y, a0.z, a0.w);
            ROT(v[r][0].z, v[r][2].z, a1.x, a1.y);
            ROT(v[r][0].w, v[r][2].w, a1.z, a1.w);
            ROT(v[r][1].x, v[r][3].x, b0.x, b0.y);
            ROT(v[r][1].y, v[r][3].y, b0.z, b0.w);
            ROT(v[r][1].z, v[r][3].z, b1.x, b1.y);
            ROT(v[r][1].w, v[r][3].w, b1.z, b1.w);
        }
    }

#pragma unroll
    for (int r = 0; r < BF_R; ++r) {
        if (row0 + r < n_rows) {
#pragma unroll
            for (int mh = 0; mh < 4; ++mh)
                *reinterpret_cast<float4*>(orr + r * BF_DIM + mh * 256 + lane * 4) = v[r][mh];
        }
    }
}

extern "C" void kernel_launch(void* const* d_in, const int* in_sizes, int n_in,
                              void* d_out, int out_size, void* d_ws, size_t ws_size,
                              hipStream_t stream) {
    const float* x      = (const float*)d_in[0];
    const float* angles = (const float*)d_in[1];
    float*       out    = (float*)d_out;
    float2*      cs     = (float2*)d_ws;   // 10*512*8 = 40960 bytes

    const int ncs = BF_STAGES * (BF_DIM / 2);
    bf_fill_cs<<<(ncs + 255) / 256, 256, 0, stream>>>(angles, cs, ncs);

    const int rows   = in_sizes[0] / BF_DIM;
    const int waves  = (rows + BF_R - 1) / BF_R;
    const int blocks = (waves + 3) / 4;   // 4 waves per 256-thread block
    bf_butterfly<<<blocks, 256, 0, stream>>>(x, (const float4*)cs, out, rows);
}